// Round 9
// baseline (254.818 us; speedup 1.0000x reference)
//
#include <hip/hip_runtime.h>

// ConvLSTM1D fused scan for MI355X — f32 I/O, bf16 MFMA.
// Round 15: r9 structure (113us champion: 256 thr, wave owns slots
// {m, m+4}, reg-held prepermuted B-tables) + four independent micro-deltas:
//  (1) SIMD load-balance rotation: wave w serves slot m = (w + rot)&3 with
//      rot = 2*(bit0^bit8 of blockIdx). Co-resident blocks (2c/2c+1 or
//      c/c+256 pairing) then differ by rot=2, so the per-SIMD slot load at
//      nmt=6 becomes 3,3,3,3 instead of 4,3,2,3 — the barrier stops waiting
//      on a structurally overloaded SIMD. Work identical.
//  (2) q<2 guard on x prefetch (r14-proven: FETCH 99.5->76.5 MB, fewer ops).
//  (3) ax built with v_perm_b32 (bit-identical to f2b_trunc, -8 ops/step).
//  (4) tanh via exp2(x*2log2e): drops the separate 2*x mul (<=1ulp arg delta,
//      far under bf16 h-storage noise).
// Lessons that bound this design (measured): cross-block comm fatal (r8/r13);
// launch_bounds caps below ~196 regs spill the B-file (r10); more waves or
// more blocks at same work never paid (r7/r11/r12/r14) — only work reduction
// moves the wall, at ~2.2x leverage (r9).
// Halo-tile trick: block owns j-range [j0, j0+64); recurrent conv reads h[j+1]
// only, so a right halo that starts at +49 rows and shrinks by 1 per step makes
// every block's 50-step scan fully independent (no grid sync).

#define TT 50
#define LTILE 64
#define ROWS 129   // 64 owned + 49 halo + 1 read-halo row (row 128 stays 0)
#define HSTR 40    // h row stride (shorts); mult of 8 -> 16B-aligned ds_read_b128

typedef __attribute__((ext_vector_type(8))) short short8;
typedef __attribute__((ext_vector_type(4))) float floatx4;

// Prepermuted bf16 weight fragment tables: index [n*64 + lane].
__device__ short8 g_tw0[512];   // rec_kernel tap rows 0..31  (k = q*8+j)
__device__ short8 g_tw1[512];   // rec_kernel tap rows 32..63
__device__ short8 g_txw[512];   // x-conv taps (k rows 0..15) + bias row 16

__device__ __forceinline__ unsigned short f2b_rne(float f) {
  union { float f; unsigned u; } v; v.f = f;
  unsigned r = v.u + 0x7FFFu + ((v.u >> 16) & 1u);
  return (unsigned short)(r >> 16);
}
__device__ __forceinline__ float hsig(float x) {
  return __builtin_amdgcn_fmed3f(__builtin_fmaf(0.2f, x, 0.5f), 0.0f, 1.0f);
}
__device__ __forceinline__ float ftanh(float x) {
  // tanh(x) = 1 - 2/(exp2(x*2*log2e)+1); v_exp_f32 IS exp2 -> saves the 2*x mul
  float e = __builtin_amdgcn_exp2f(x * 2.88539008177792681472f);
  return 1.0f - 2.0f * __builtin_amdgcn_rcpf(e + 1.0f);
}

// ---- prep: fragment tables (512 threads: one per (n,lane)) + zero ws.
__global__ void prep(const float* __restrict__ ks,
                     const float* __restrict__ rks,
                     const float* __restrict__ bs,
                     float* __restrict__ ws) {
  const int tid  = threadIdx.x;        // 0..511
  const int n    = tid >> 6;
  const int lane = tid & 63;
  const int q    = lane >> 4;
  const int f0   = lane & 15;
  if (tid < 32) ws[tid] = 0.0f;

  // Gate-pair permutation: tile n = 2g+p, col f0  <->  oc = g*32 + 2*f0 + p
  const int oc = (n >> 1) * 32 + 2 * f0 + (n & 1);
  short8 th;
#pragma unroll
  for (int j = 0; j < 8; ++j)
    th[j] = (short)f2b_rne(rks[(q * 8 + j) * 128 + oc]);
  g_tw0[n * 64 + lane] = th;
#pragma unroll
  for (int j = 0; j < 8; ++j)
    th[j] = (short)f2b_rne(rks[(32 + q * 8 + j) * 128 + oc]);
  g_tw1[n * 64 + lane] = th;
  // x-conv B: k rows 0..7 = tap0, 8..15 = tap1 (paired with x_hi),
  // row 16 = bias (ax carries 1.0 there), rows 17..31 = 0.
  short8 tx = {0, 0, 0, 0, 0, 0, 0, 0};
  if (q < 2) {
#pragma unroll
    for (int j = 0; j < 8; ++j)
      tx[j] = (short)f2b_rne(ks[(q * 8 + j) * 128 + oc]);
  } else if (q == 2) {
    tx[0] = (short)f2b_rne(bs[oc]);
  }
  g_txw[n * 64 + lane] = tx;
}

__global__ __launch_bounds__(256, 2)
void convlstm_scan(const float* __restrict__ xs,   // x [32][50][2048][8] f32
                   const float* __restrict__ dws,  // dense_w [32768] f32
                   float* __restrict__ acc_out) {  // [32] f32 accumulators
  __shared__ short hbH[2][ROWS * HSTR];   // h (bf16), double-buffered, 20.6 KB

  const int tid  = threadIdx.x;
  const int b    = blockIdx.x >> 4;
  const int j0   = (blockIdx.x & 15) * LTILE;
  const int wave = tid >> 6;
  const int lane = tid & 63;
  const int q    = lane >> 4;
  const int f0   = lane & 15;
  // (1) per-block slot rotation: co-resident blocks differ by rot=2
  const int rot  = 2 * ((blockIdx.x ^ (blockIdx.x >> 8)) & 1);
  const int mrot = (wave + rot) & 3;       // this wave's slot pair {mrot, mrot+4}

  for (int e = tid; e < ROWS * HSTR; e += 256)   // ints cover both buffers
    ((int*)hbH)[e] = 0;

  // ---- B fragments: coalesced loads from the prepermuted tables.
  // tile n = 2g+p, col f0  <->  oc = g*32 + 2*f0 + p  => lane f0's two
  // outputs per row are adjacent h-cols 2f0, 2f0+1 (packed b32 store).
  short8 Bwh0[8], Bwh1[8], Bxw[8];
#pragma unroll
  for (int n = 0; n < 8; ++n) {
    Bwh0[n] = g_tw0[n * 64 + lane];
    Bwh1[n] = g_tw1[n * 64 + lane];
    Bxw[n]  = g_txw[n * 64 + lane];
  }

  // ax constant part: lane (q=2, elem 0) = bf16 1.0 (bias marker), else 0.
  short8 axc = {0, 0, 0, 0, 0, 0, 0, 0};
  if (q == 2) axc[0] = (short)0x3F80;

  const floatx4 zero4 = {0.0f, 0.0f, 0.0f, 0.0f};

  float cst[2][8];   // c-state, MFMA C-layout: [m-slot][p*4 + r]
#pragma unroll
  for (int s = 0; s < 2; ++s)
#pragma unroll
    for (int i = 0; i < 8; ++i) cst[s][i] = 0.0f;

  // ---- initial x prefetch (t=0); only q<2 lanes feed ax
  floatx4 px0[2], px1[2];
#pragma unroll
  for (int s = 0; s < 2; ++s) {
    px0[s] = zero4; px1[s] = zero4;
    const int jr = (mrot + 4 * s) * 16 + f0;
    const int jm = min(j0 + jr, 1023);
    if (q < 2) {
      const float* xp = xs + (size_t)b * TT * (2048 * 8) +
                        (size_t)(2 * jm + q) * 8;
      px0[s] = *(const floatx4*)xp;
      px1[s] = *(const floatx4*)(xp + 4);
    }
  }

  const int maxrows = 1024 - j0;
  float part = 0.0f;                        // fused Dense(1) partial
  __syncthreads();

  for (int t = 0; t < TT; ++t) {
    const short* curH = hbH[t & 1];
    short* nxtH = hbH[(t & 1) ^ 1];
    int rows = LTILE + (TT - 1) - t;          // halo shrinks 1/step
    if (rows > maxrows) rows = maxrows;
    const int nmt = (rows + 15) >> 4;         // 4..8; slot0 (mrot<4) always live
    const int act1 = (mrot + 4) < nmt;        // wave-uniform slot1 guard
    const int last = (t == TT - 1);
    const int tn = last ? t : t + 1;
    const float* xnext = xs + ((size_t)(b * TT + tn)) * (2048 * 8);

    // 1) Front-load a-frag LDS reads (max read row = 128 = ROWS-1, stays 0).
    short8 a0h[2], a1h[2];
#pragma unroll
    for (int s = 0; s < 2; ++s) {
      if (s == 1 && !act1) continue;
      const int jr = (mrot + 4 * s) * 16 + f0;
      a0h[s] = *(const short8*)&curH[jr * HSTR + q * 8];
      a1h[s] = *(const short8*)&curH[(jr + 1) * HSTR + q * 8];
    }

    // 2) Build ax (x_hi) via v_perm byte-pick (== pair of bf16-truncs).
    short8 ax[2];
#pragma unroll
    for (int s = 0; s < 2; ++s) {
      ax[s] = axc;
      if (q < 2) {
        unsigned* axw = (unsigned*)&ax[s];
        axw[0] = __builtin_amdgcn_perm(__float_as_uint(px0[s][1]),
                                       __float_as_uint(px0[s][0]), 0x07060302u);
        axw[1] = __builtin_amdgcn_perm(__float_as_uint(px0[s][3]),
                                       __float_as_uint(px0[s][2]), 0x07060302u);
        axw[2] = __builtin_amdgcn_perm(__float_as_uint(px1[s][1]),
                                       __float_as_uint(px1[s][0]), 0x07060302u);
        axw[3] = __builtin_amdgcn_perm(__float_as_uint(px1[s][3]),
                                       __float_as_uint(px1[s][2]), 0x07060302u);
      }
    }

    // 3) Issue next-step x prefetch (longest latency, overlaps MFMA below).
#pragma unroll
    for (int s = 0; s < 2; ++s) {
      if (q >= 2) continue;
      const int jr = (mrot + 4 * s) * 16 + f0;
      const int jm = min(j0 + jr, 1023);
      const float* xp = xnext + (size_t)(2 * jm + q) * 8;
      px0[s] = *(const floatx4*)xp;
      px1[s] = *(const floatx4*)(xp + 4);
    }

    // 4) Per-slot MFMA + pointwise.
#pragma unroll
    for (int s = 0; s < 2; ++s) {
      if (s == 1 && !act1) continue;
      const int m = mrot + 4 * s;

      floatx4 acc[8];
      // ax first: operands in registers, C = zero4; issues while ds_reads land.
#pragma unroll
      for (int n = 0; n < 8; ++n)
        acc[n] = __builtin_amdgcn_mfma_f32_16x16x32_bf16(ax[s], Bxw[n], zero4, 0, 0, 0);
#pragma unroll
      for (int n = 0; n < 8; ++n)
        acc[n] = __builtin_amdgcn_mfma_f32_16x16x32_bf16(a0h[s], Bwh0[n], acc[n], 0, 0, 0);
#pragma unroll
      for (int n = 0; n < 8; ++n)
        acc[n] = __builtin_amdgcn_mfma_f32_16x16x32_bf16(a1h[s], Bwh1[n], acc[n], 0, 0, 0);

      // Pointwise LSTM. D[m-row = q*4+r][tile n, col f0 -> h-col 2f0 + (n&1)].
      // Gate g in tiles {2g, 2g+1}: zi=acc[0+p], zf=acc[2+p], zc=acc[4+p],
      // zo=acc[6+p] give h-col 2f0+p.
      const int jw = m * 16 + q * 4;
#pragma unroll
      for (int r = 0; r < 4; ++r) {
        float hv2[2];
#pragma unroll
        for (int p = 0; p < 2; ++p) {
          float zi = acc[0 + p][r], zf = acc[2 + p][r];
          float zc = acc[4 + p][r], zo = acc[6 + p][r];
          float ig = hsig(zi), fg = hsig(zf), og = hsig(zo);
          float cs = cst[s][p * 4 + r];
          float cn = __builtin_fmaf(fg, cs, ig * ftanh(zc));
          cst[s][p * 4 + r] = cn;
          hv2[p] = og * ftanh(cn);
        }
        if (!last) {
          unsigned pk;
          asm("v_cvt_pk_bf16_f32 %0, %1, %2"
              : "=v"(pk) : "v"(hv2[0]), "v"(hv2[1]));
          *(unsigned*)&nxtH[(jw + r) * HSTR + 2 * f0] = pk;
        } else {
          // t=49: nmt=4, s=0 only; slots {mrot} over 4 waves cover [0,64).
          const int di = (j0 + jw + r) * 32 + 2 * f0;
          part = __builtin_fmaf(hv2[0], dws[di],
                 __builtin_fmaf(hv2[1], dws[di + 1], part));
        }
      }
    }
    __syncthreads();
  }

  // ---- reduce fused-dense partials
#pragma unroll
  for (int off = 32; off > 0; off >>= 1) part += __shfl_down(part, off);
  if (lane == 0) atomicAdd(&acc_out[b], part);
}

__global__ void finalize(const float* __restrict__ ws,
                         const float* __restrict__ db,
                         float* __restrict__ out) {
  int i = threadIdx.x;
  if (i < 32) out[i] = ws[i] + db[0];
}

extern "C" void kernel_launch(void* const* d_in, const int* in_sizes, int n_in,
                              void* d_out, int out_size, void* d_ws, size_t ws_size,
                              hipStream_t stream) {
  const float* x  = (const float*)d_in[0];
  const float* k  = (const float*)d_in[1];
  const float* rk = (const float*)d_in[2];
  const float* bi = (const float*)d_in[3];
  const float* dw = (const float*)d_in[4];
  const float* db = (const float*)d_in[5];
  float* ws = (float*)d_ws;
  float* out = (float*)d_out;

  hipLaunchKernelGGL(prep, dim3(1), dim3(512), 0, stream, k, rk, bi, ws);
  hipLaunchKernelGGL(convlstm_scan, dim3(512), dim3(256), 0, stream,
                     x, dw, ws);
  hipLaunchKernelGGL(finalize, dim3(1), dim3(64), 0, stream, ws, db, out);
}